// Round 12
// baseline (504.956 us; speedup 1.0000x reference)
//
#include <hip/hip_runtime.h>
#include <hip/hip_bf16.h>

#define B_ 8
#define N_ 2048
#define D_ 32
#define RCAP 16                        // CSR entries per row (P(row>16) ~ 1e-15)
#define EM1_DIAG 1.7182818284590452f   // e^1 - 1
#define M_   8.0f
#define EM_  2980.9579870417283f       // e^8
#define L2E  1.4426950408889634f
#define LN2  0.6931471805599453f
#define MH_  (0.5f * M_ * L2E)         // 0.5*M in base-2 units

typedef __attribute__((ext_vector_type(8))) short short8;
typedef __attribute__((ext_vector_type(4))) float f32x4;

// ---------------------------------------------------------------------------
// Setup: bf16 copies of x,y, half-norms ||r||^2/2, zero the CSR counters.
// ---------------------------------------------------------------------------
__global__ void setup_kernel(const float* __restrict__ x, const float* __restrict__ y,
                             unsigned short* __restrict__ xb, unsigned short* __restrict__ yb,
                             float* __restrict__ NX, float* __restrict__ NY,
                             int* __restrict__ csr_cnt)
{
    int t = blockIdx.x * 256 + threadIdx.x;          // 0..32767
    const float* src = (t < 16384) ? x : y;
    unsigned short* dstb = (t < 16384) ? xb : yb;
    float* dstn = (t < 16384) ? NX : NY;
    int row = (t < 16384) ? t : (t - 16384);
    const float4* p = reinterpret_cast<const float4*>(src + (size_t)row * D_);
    float ss = 0.f;
    float4 v[8];
    #pragma unroll
    for (int k = 0; k < 8; k++) {
        v[k] = p[k];
        ss += v[k].x * v[k].x + v[k].y * v[k].y + v[k].z * v[k].z + v[k].w * v[k].w;
    }
    short8* dst8 = reinterpret_cast<short8*>(dstb + (size_t)row * D_);
    #pragma unroll
    for (int k = 0; k < 4; k++) {
        const float fv[8] = { v[2*k].x, v[2*k].y, v[2*k].z, v[2*k].w,
                              v[2*k+1].x, v[2*k+1].y, v[2*k+1].z, v[2*k+1].w };
        short8 o;
        #pragma unroll
        for (int e = 0; e < 8; e++) {
            __hip_bfloat16 h = __float2bfloat16(fv[e]);
            o[e] = *reinterpret_cast<const short*>(&h);
        }
        dst8[k] = o;
    }
    dstn[row] = ss * 0.5f;
    csr_cnt[2 * t] = 0;                              // 4*8*2048 = 65536 counters
    csr_cnt[2 * t + 1] = 0;
}

// ---------------------------------------------------------------------------
// Pair discovery. 3072 blocks, store/atomic-free phase-1 mask scan; phase 2
// re-walks survivors and emits row-CSR entries (col, e^G - 1) into tables
// 0=xx, 1=yy, 2=yx, 3=xy(=yx^T).
// ---------------------------------------------------------------------------
__global__ __launch_bounds__(256) void discover_kernel(
    const unsigned short* __restrict__ xb, const unsigned short* __restrict__ yb,
    const float* __restrict__ NX, const float* __restrict__ NY,
    int* __restrict__ csr_cnt, uint2* __restrict__ csr_ent)
{
    int m = blockIdx.x >> 10;                         // matrix 0=xx 1=yy 2=yx
    int rem = blockIdx.x & 1023;
    int batch = rem >> 7;                             // 8 batches
    int rem2 = rem & 127;
    int rowblk = rem2 >> 2;                           // 32 blocks of 64 rows
    int cchunk = rem2 & 3;                            // 4 chunks of 512 cols
    const unsigned short* rd = (m == 0) ? xb : yb;
    const float*          rN = (m == 0) ? NX : NY;
    const unsigned short* cd = (m == 1) ? yb : xb;
    const float*          cN = (m == 1) ? NY : NX;

    const int tid = threadIdx.x, lane = tid & 63, wv = tid >> 6;
    const int r0 = rowblk * 64;
    const size_t rowbase = (size_t)batch * N_ + r0;

    short8 afrag[4];
    f32x4 cinit[4];
    #pragma unroll
    for (int g = 0; g < 4; g++) {
        afrag[g] = *reinterpret_cast<const short8*>(
            rd + (rowbase + g * 16 + (lane & 15)) * D_ + (lane >> 4) * 8);
        float4 nv = *reinterpret_cast<const float4*>(
            rN + rowbase + g * 16 + (lane >> 4) * 4);
        cinit[g][0] = -nv.x; cinit[g][1] = -nv.y; cinit[g][2] = -nv.z; cinit[g][3] = -nv.w;
    }
    const unsigned short* cdB = cd + (size_t)batch * N_ * D_;
    const float* cNB = cN + batch * N_;
    const int c0w = cchunk * 512 + wv * 128;

    // ---- phase 1: branch-free survivor scan -------------------------------
    unsigned mask = 0;
    #pragma unroll
    for (int cc = 0; cc < 8; ++cc) {
        int col = c0w + cc * 16 + (lane & 15);
        short8 bfrag = *reinterpret_cast<const short8*>(
            cdB + (size_t)col * D_ + (lane >> 4) * 8);
        float ny = cNB[col];
        f32x4 d[4];
        #pragma unroll
        for (int g = 0; g < 4; g++)
            d[g] = __builtin_amdgcn_mfma_f32_16x16x32_bf16(afrag[g], bfrag, cinit[g], 0, 0, 0);
        float m0 = fmaxf(fmaxf(d[0][0], d[0][1]), fmaxf(d[0][2], d[0][3]));
        float m1 = fmaxf(fmaxf(d[1][0], d[1][1]), fmaxf(d[1][2], d[1][3]));
        float m2 = fmaxf(fmaxf(d[2][0], d[2][1]), fmaxf(d[2][2], d[2][3]));
        float m3 = fmaxf(fmaxf(d[3][0], d[3][1]), fmaxf(d[3][2], d[3][3]));
        float mx = fmaxf(fmaxf(m0, m1), fmaxf(m2, m3));
        mask |= (__any(mx > ny - 10.0f) ? 1u : 0u) << cc;
    }

    // ---- phase 2: emit (rare) ---------------------------------------------
    auto push = [&](int T, int row, int colv, float em1) {
        size_t base = (size_t)(T * B_ + batch) * N_ + row;
        int idx = atomicAdd(&csr_cnt[base], 1);
        if (idx < RCAP)
            csr_ent[base * RCAP + idx] = make_uint2((unsigned)colv, __float_as_uint(em1));
    };
    while (mask) {
        int cc = __builtin_ctz(mask);
        mask &= mask - 1;
        int col = c0w + cc * 16 + (lane & 15);
        short8 bfrag = *reinterpret_cast<const short8*>(
            cdB + (size_t)col * D_ + (lane >> 4) * 8);
        float ny = cNB[col];
        f32x4 d[4];
        #pragma unroll
        for (int g = 0; g < 4; g++)
            d[g] = __builtin_amdgcn_mfma_f32_16x16x32_bf16(afrag[g], bfrag, cinit[g], 0, 0, 0);
        #pragma unroll
        for (int g = 0; g < 4; g++) {
            #pragma unroll
            for (int r = 0; r < 4; r++) {
                float dist = ny - d[g][r];
                if (dist < 10.0f) {
                    int i = r0 + g * 16 + (lane >> 4) * 4 + r;
                    if (m == 2) {
                        float em1 = __expf(__expf(-fmaxf(dist, 0.f))) - 1.0f;
                        push(2, i, col, em1);
                        push(3, col, i, em1);
                    } else if (i != col) {
                        float em1 = __expf(__expf(-fmaxf(dist, 0.f))) - 1.0f;
                        push(m, i, col, em1);
                    }
                }
            }
        }
    }
}

// ---------------------------------------------------------------------------
// ZERO-BARRIER wave-synchronous Sinkhorn. One 192-thread block per batch.
// The Gauss-Seidel order factorizes into 3 independent chains:
//   wave0: fyx/fxy alternating x20 (fyx uses old fxy; fxy uses new fyx)
//   wave1: fxx x10      wave2: fyy x10
// Each wave runs its chain alone: 32 cols/lane in registers, ev published to
// a PRIVATE LDS buffer (same-wave lgkmcnt ordering, no barrier), S via 6-deep
// in-wave shfl, CSR gather via predicated global loads (L2-hot, unrolled).
// Extrapolation LSEs split per wave (uses only that wave's potentials), ONE
// __syncthreads in the whole kernel to combine the weighted partials.
// This removes everything R7-R11 shared (multi-wave barriers, cross-wave
// reduces) - the discriminating test for the per-stage cost.
// ---------------------------------------------------------------------------
__global__ __launch_bounds__(192) void sinkhorn_kernel(
    const float* __restrict__ a_in, const float* __restrict__ b_in,
    const int* __restrict__ csr_cnt, const uint2* __restrict__ csr_ent,
    float* __restrict__ out)
{
    __shared__ float evb[3][N_];        // 24 KB, one buffer per wave
    __shared__ float slot[3];

    const int batch = blockIdx.x;
    const int t = threadIdx.x, wv = t >> 6, lane = t & 63;
    float partial = 0.f;

    if (wv == 0) {
        // ---------------- yx/xy chain (20 stages) + 2 ext LSEs -------------
        float AW[32], BW[32], FY[32], FX[32];   // FY = fyx (y rows), FX = fxy (x rows)
        unsigned cp2[4] = {0,0,0,0}, cp3[4] = {0,0,0,0};
        const size_t bb2 = (size_t)(2 * B_ + batch) * N_;
        const size_t bb3 = (size_t)(3 * B_ + batch) * N_;
        #pragma unroll
        for (int k = 0; k < 32; k++) {
            int j = lane + 64 * k;
            AW[k] = (a_in[batch * N_ + j] - M_) * L2E;
            BW[k] = (b_in[batch * N_ + j] - M_) * L2E;
            FY[k] = 0.f; FX[k] = 0.f;
            cp2[k >> 3] |= (unsigned)min(csr_cnt[bb2 + j], 15) << ((k & 7) * 4);
            cp3[k >> 3] |= (unsigned)min(csr_cnt[bb3 + j], 15) << ((k & 7) * 4);
        }
        const uint2* E2 = csr_ent + bb2 * (size_t)RCAP;
        const uint2* E3 = csr_ent + bb3 * (size_t)RCAP;
        float* ev = evb[0];

        // fyx stage: cols x (AW+FX) -> ev; rows y, table T2; update FY
        auto stageYX = [&](bool ext) {
            float s = 0.f;
            #pragma unroll
            for (int k = 0; k < 32; k++) {
                float e = __builtin_amdgcn_exp2f(AW[k] + FX[k]);
                ev[lane + 64 * k] = e; s += e;
            }
            #pragma unroll
            for (int off = 1; off < 64; off <<= 1) s += __shfl_xor(s, off, 64);
            #pragma unroll
            for (int k = 0; k < 32; k++) {
                float g = 0.f;
                int nib = (cp2[k >> 3] >> ((k & 7) * 4)) & 15;
                if (nib) {
                    const uint2* E = E2 + (size_t)(lane + 64 * k) * RCAP;
                    g += ev[E[0].x] * __uint_as_float(E[0].y);
                    if (nib > 1) g += ev[E[1].x] * __uint_as_float(E[1].y);
                    if (nib > 2)
                        for (int e2 = 2; e2 < nib; ++e2)
                            g += ev[E[e2].x] * __uint_as_float(E[e2].y);
                }
                float lg = __builtin_amdgcn_logf(s + g);       // log2
                if (!ext) FY[k] = fmaf(0.5f, FY[k], -fmaf(0.5f, lg, MH_));
                else      partial -= lg * __builtin_amdgcn_exp2f(BW[k]);  // -lse_yx * e^{b-M}
            }
        };
        // fxy stage: cols y (BW+FY) -> ev; rows x, table T3; update FX
        auto stageXY = [&](bool ext) {
            float s = 0.f;
            #pragma unroll
            for (int k = 0; k < 32; k++) {
                float e = __builtin_amdgcn_exp2f(BW[k] + FY[k]);
                ev[lane + 64 * k] = e; s += e;
            }
            #pragma unroll
            for (int off = 1; off < 64; off <<= 1) s += __shfl_xor(s, off, 64);
            #pragma unroll
            for (int k = 0; k < 32; k++) {
                float g = 0.f;
                int nib = (cp3[k >> 3] >> ((k & 7) * 4)) & 15;
                if (nib) {
                    const uint2* E = E3 + (size_t)(lane + 64 * k) * RCAP;
                    g += ev[E[0].x] * __uint_as_float(E[0].y);
                    if (nib > 1) g += ev[E[1].x] * __uint_as_float(E[1].y);
                    if (nib > 2)
                        for (int e2 = 2; e2 < nib; ++e2)
                            g += ev[E[e2].x] * __uint_as_float(E[e2].y);
                }
                float lg = __builtin_amdgcn_logf(s + g);
                if (!ext) FX[k] = fmaf(0.5f, FX[k], -fmaf(0.5f, lg, MH_));
                else      partial -= lg * __builtin_amdgcn_exp2f(AW[k]);  // -lse_xy * e^{a-M}
            }
        };
        for (int it = 0; it < 10; ++it) { stageYX(false); stageXY(false); }
        stageYX(true);   // fe_yx with final fxy
        stageXY(true);   // fe_xy with final fyx
    } else {
        // ---------------- xx chain (wave1) / yy chain (wave2) --------------
        const int T = (wv == 1) ? 0 : 1;
        const float* w_in = (wv == 1) ? a_in : b_in;
        float W[32], F[32], e[32];
        unsigned cp[4] = {0,0,0,0};
        const size_t bb = (size_t)(T * B_ + batch) * N_;
        #pragma unroll
        for (int k = 0; k < 32; k++) {
            int j = lane + 64 * k;
            W[k] = (w_in[batch * N_ + j] - M_) * L2E;
            F[k] = 0.f;
            cp[k >> 3] |= (unsigned)min(csr_cnt[bb + j], 15) << ((k & 7) * 4);
        }
        const uint2* Eb = csr_ent + bb * (size_t)RCAP;
        float* ev = evb[wv];

        auto stage = [&](bool ext) {
            float s = 0.f;
            #pragma unroll
            for (int k = 0; k < 32; k++) {
                e[k] = __builtin_amdgcn_exp2f(W[k] + F[k]);
                ev[lane + 64 * k] = e[k]; s += e[k];
            }
            #pragma unroll
            for (int off = 1; off < 64; off <<= 1) s += __shfl_xor(s, off, 64);
            #pragma unroll
            for (int k = 0; k < 32; k++) {
                float g = e[k] * EM1_DIAG;                    // exact diagonal
                int nib = (cp[k >> 3] >> ((k & 7) * 4)) & 15;
                if (nib) {
                    const uint2* E = Eb + (size_t)(lane + 64 * k) * RCAP;
                    g += ev[E[0].x] * __uint_as_float(E[0].y);
                    if (nib > 1) g += ev[E[1].x] * __uint_as_float(E[1].y);
                    if (nib > 2)
                        for (int e2 = 2; e2 < nib; ++e2)
                            g += ev[E[e2].x] * __uint_as_float(E[e2].y);
                }
                float lg = __builtin_amdgcn_logf(s + g);
                if (!ext) F[k] = fmaf(0.5f, F[k], -fmaf(0.5f, lg, MH_));
                else      partial += lg * __builtin_amdgcn_exp2f(W[k]);   // +lse * e^{w-M}
            }
        };
        for (int it = 0; it < 10; ++it) stage(false);
        stage(true);     // fe_xx (wave1) / fe_yy (wave2)
    }

    // res = sum_l (lse_xx - lse_xy) e^a + sum_k (lse_yy - lse_yx) e^b, then
    // scale by LN2 (log2->ln) and EM_ (restore the -M in e^{w-M}); M cancels.
    #pragma unroll
    for (int off = 1; off < 64; off <<= 1) partial += __shfl_xor(partial, off, 64);
    if (lane == 0) slot[wv] = partial;
    __syncthreads();
    if (t == 0) out[batch] = (slot[0] + slot[1] + slot[2]) * (LN2 * EM_);
}

// ---------------------------------------------------------------------------
extern "C" void kernel_launch(void* const* d_in, const int* in_sizes, int n_in,
                              void* d_out, int out_size, void* d_ws, size_t ws_size,
                              hipStream_t stream)
{
    const float* x = (const float*)d_in[0];
    const float* a = (const float*)d_in[1];
    const float* y = (const float*)d_in[2];
    const float* b = (const float*)d_in[3];
    float* out = (float*)d_out;

    char* ws = (char*)d_ws;
    size_t o = 0;
    unsigned short* xb = (unsigned short*)(ws + o); o += (size_t)B_ * N_ * D_ * 2;
    unsigned short* yb = (unsigned short*)(ws + o); o += (size_t)B_ * N_ * D_ * 2;
    float* NX = (float*)(ws + o); o += (size_t)B_ * N_ * 4;
    float* NY = (float*)(ws + o); o += (size_t)B_ * N_ * 4;
    int* csr_cnt = (int*)(ws + o); o += (size_t)4 * B_ * N_ * 4;            // 256 KB
    uint2* csr_ent = (uint2*)(ws + o); o += (size_t)4 * B_ * N_ * RCAP * 8; // 8 MB

    setup_kernel<<<128, 256, 0, stream>>>(x, y, xb, yb, NX, NY, csr_cnt);
    discover_kernel<<<3 * 1024, 256, 0, stream>>>(xb, yb, NX, NY, csr_cnt, csr_ent);
    sinkhorn_kernel<<<B_, 192, 0, stream>>>(a, b, csr_cnt, csr_ent, out);
}